// Round 6
// baseline (323.409 us; speedup 1.0000x reference)
//
#include <hip/hip_runtime.h>
#include <hip/hip_bf16.h>
#include <math.h>

// Problem constants
#define B_   2
#define T_   2048
#define D_   2048
#define NH_  16
#define NKV_ 4
#define HD_  128
#define MROWS (B_*T_)          // 4096
#define NQKV  (NH_*HD_ + 2*NKV_*HD_)  // 3072

typedef __bf16 bf16_t;
typedef __bf16 bf16x8 __attribute__((ext_vector_type(8)));
typedef __bf16 bf16x4 __attribute__((ext_vector_type(4)));
typedef float  floatx4 __attribute__((ext_vector_type(4)));

// ---------------------------------------------------------------------------
// async global->LDS, 16B per lane. LDS dest must be wave-uniform base + lane*16.
__device__ __forceinline__ void async_copy16(const bf16_t* gsrc, bf16_t* ldst) {
  __builtin_amdgcn_global_load_lds(
      (const __attribute__((address_space(1))) unsigned int*)gsrc,
      (__attribute__((address_space(3))) unsigned int*)ldst, 16, 0, 0);
}

// ---------------------------------------------------------------------------
// cast fp32 -> bf16, 8 elems/thread
__global__ void cast_f32_bf16(const float* __restrict__ src, bf16_t* __restrict__ dst, int n) {
  int i = (blockIdx.x * 256 + threadIdx.x) * 8;
  if (i >= n) return;
  float4 a = *(const float4*)(src + i);
  float4 b = *(const float4*)(src + i + 4);
  bf16x8 v;
  v[0]=(bf16_t)a.x; v[1]=(bf16_t)a.y; v[2]=(bf16_t)a.z; v[3]=(bf16_t)a.w;
  v[4]=(bf16_t)b.x; v[5]=(bf16_t)b.y; v[6]=(bf16_t)b.z; v[7]=(bf16_t)b.w;
  *(bf16x8*)(dst + i) = v;
}

// ---------------------------------------------------------------------------
// transpose + cast: src (K,N) fp32 row-major -> dst (N,K) bf16 row-major
// grid (N/32, K/32), block (32,8)
__global__ void transpose_cast(const float* __restrict__ src, bf16_t* __restrict__ dst,
                               int K, int N) {
  __shared__ float tile[32][33];
  int n0 = blockIdx.x * 32, k0 = blockIdx.y * 32;
  int tx = threadIdx.x, ty = threadIdx.y;
#pragma unroll
  for (int r = 0; r < 4; r++)
    tile[ty + r*8][tx] = src[(size_t)(k0 + ty + r*8) * N + n0 + tx];
  __syncthreads();
#pragma unroll
  for (int r = 0; r < 4; r++)
    dst[(size_t)(n0 + ty + r*8) * K + k0 + tx] = (bf16_t)tile[tx][ty + r*8];
}

// ---------------------------------------------------------------------------
// C(M,N) = A(M,K) * Bt(N,K)^T   all bf16 in, OUT_T out.
// 128x128 tile, BK=64, 4 waves (2x2 of 64x64), 16x16x32 MFMA.
template <typename OUT_T>
__global__ __launch_bounds__(256, 2)
void gemm_bt(const bf16_t* __restrict__ A, const bf16_t* __restrict__ Bt,
             OUT_T* __restrict__ C, int M, int N, int K) {
  __shared__ __align__(16) bf16_t As[128 * 64];
  __shared__ __align__(16) bf16_t Bs[128 * 64];
  const int tid  = threadIdx.x;
  const int wave = tid >> 6, lane = tid & 63;
  const int quad = lane >> 4, l16 = lane & 15;
  const int nBlocksM = M >> 7;
  const int bm = blockIdx.x % nBlocksM, bn = blockIdx.x / nBlocksM;
  const int m0 = bm * 128, n0 = bn * 128;
  const int wm = (wave >> 1) * 64, wn = (wave & 1) * 64;

  floatx4 acc[4][4];
#pragma unroll
  for (int i = 0; i < 4; i++)
#pragma unroll
    for (int j = 0; j < 4; j++) acc[i][j] = floatx4{0.f, 0.f, 0.f, 0.f};

  for (int k0 = 0; k0 < K; k0 += 64) {
    __syncthreads();
#pragma unroll
    for (int i = 0; i < 4; i++) {
      int e = i * 256 + tid;
      int row = e >> 3, grp = e & 7;
      int gg = grp ^ (row & 7);
      async_copy16(A + (size_t)(m0 + row) * K + k0 + gg * 8, As + e * 8);
    }
#pragma unroll
    for (int i = 0; i < 4; i++) {
      int e = i * 256 + tid;
      int row = e >> 3, grp = e & 7;
      int gg = grp ^ (row & 7);
      async_copy16(Bt + (size_t)(n0 + row) * K + k0 + gg * 8, Bs + e * 8);
    }
    __syncthreads();
#pragma unroll
    for (int ks = 0; ks < 2; ks++) {
      bf16x8 af[4], bfr[4];
      int grp = ks * 4 + quad;
#pragma unroll
      for (int mi = 0; mi < 4; mi++) {
        int row = wm + mi * 16 + l16;
        af[mi] = *(const bf16x8*)(As + row * 64 + ((grp ^ (row & 7)) << 3));
      }
#pragma unroll
      for (int ni = 0; ni < 4; ni++) {
        int row = wn + ni * 16 + l16;
        bfr[ni] = *(const bf16x8*)(Bs + row * 64 + ((grp ^ (row & 7)) << 3));
      }
#pragma unroll
      for (int mi = 0; mi < 4; mi++)
#pragma unroll
        for (int ni = 0; ni < 4; ni++)
          acc[mi][ni] = __builtin_amdgcn_mfma_f32_16x16x32_bf16(af[mi], bfr[ni], acc[mi][ni], 0, 0, 0);
    }
  }
  // epilogue: C row = quad*4+reg (+16*mi), col = lane&15 (+16*ni)  [m89/m91 layout]
#pragma unroll
  for (int mi = 0; mi < 4; mi++) {
#pragma unroll
    for (int r = 0; r < 4; r++) {
      int row = m0 + wm + mi * 16 + quad * 4 + r;
      size_t base = (size_t)row * N + n0 + wn;
#pragma unroll
      for (int ni = 0; ni < 4; ni++)
        C[base + ni * 16 + l16] = (OUT_T)acc[mi][ni][r];
    }
  }
}

// ---------------------------------------------------------------------------
// RoPE + scatter: qkv (4096, 3072) bf16 -> Qb (B,NH,T,HD) scaled+roped,
//                 Kb (B,NKV,T,HD) roped.  One thread per (row, head, j<64).
// Q scale = 1/sqrt(128) * log2(e)  (flash softmax runs in exp2 domain)
__global__ void rope_scatter(const bf16_t* __restrict__ qkv,
                             bf16_t* __restrict__ Qb, bf16_t* __restrict__ Kb) {
  int g = blockIdx.x * 256 + threadIdx.x;
  int j = g & 63;
  int rest = g >> 6;
  int head = rest % (NH_ + NKV_);
  int row  = rest / (NH_ + NKV_);     // b*T + t
  int t = row & (T_ - 1);
  int b = row >> 11;                  // T_ = 2048
  const bf16_t* src = qkv + (size_t)row * NQKV;
  // inv_freq = 10000^(-j/64) = exp(-j * ln(10000)/64)
  float ang = (float)t * expf(-0.14391156816f * (float)j);
  float sn, cs;
  sincosf(ang, &sn, &cs);
  if (head < NH_) {
    float x0 = (float)src[head * HD_ + j];
    float x1 = (float)src[head * HD_ + 64 + j];
    const float scale = 0.12751651541057752f;  // 1/sqrt(128)*log2(e)
    bf16_t* dst = Qb + ((size_t)(b * NH_ + head) * T_ + t) * HD_;
    dst[j]      = (bf16_t)((x0 * cs - x1 * sn) * scale);
    dst[j + 64] = (bf16_t)((x1 * cs + x0 * sn) * scale);
  } else {
    int kvh = head - NH_;
    float x0 = (float)src[NH_ * HD_ + kvh * HD_ + j];
    float x1 = (float)src[NH_ * HD_ + kvh * HD_ + 64 + j];
    bf16_t* dst = Kb + ((size_t)(b * NKV_ + kvh) * T_ + t) * HD_;
    dst[j]      = (bf16_t)(x0 * cs - x1 * sn);
    dst[j + 64] = (bf16_t)(x1 * cs + x0 * sn);
  }
}

// ---------------------------------------------------------------------------
// V transpose: qkv V-slice (b,t,kv,d) -> Vt (B,NKV,HD,T)
__global__ void v_transpose(const bf16_t* __restrict__ qkv, bf16_t* __restrict__ Vt) {
  __shared__ float tile[32][33];
  int t0 = blockIdx.x * 32, d0 = blockIdx.y * 32;
  int bk = blockIdx.z;
  int b = bk / NKV_, kvh = bk % NKV_;
  int tx = threadIdx.x, ty = threadIdx.y;
#pragma unroll
  for (int r = 0; r < 4; r++) {
    int t = t0 + ty + r * 8;
    tile[ty + r*8][tx] =
        (float)qkv[(size_t)(b * T_ + t) * NQKV + (NH_ + NKV_) * HD_ + kvh * HD_ + d0 + tx];
  }
  __syncthreads();
#pragma unroll
  for (int r = 0; r < 4; r++) {
    int d = d0 + ty + r * 8;
    Vt[((size_t)(b * NKV_ + kvh) * HD_ + d) * T_ + t0 + tx] = (bf16_t)tile[tx][ty + r*8];
  }
}

// ---------------------------------------------------------------------------
// Flash attention v6: S^T formulation + COMPLEMENTARY Q-TILE PAIRING.
// One head per block; block j (of 16) owns q-tiles qta=j and qtb=31-j, so
// every block computes exactly (j+1)+(32-j)=33 tile-units: statically
// balanced across the 512-block grid (= exactly the 2-blocks/CU resident
// capacity -> no tail, no idle CUs). K/V staging (kt=0..qtb) is shared by
// both q-tiles in the overlap phase kt<=qta. Since qta<qtb always, the
// diagonal tile of b falls in the single-tile phase (uniform branches).
// Double-buffered staging, hoisted pointers, exp2 softmax, alpha-skip.
__global__ __launch_bounds__(256, 2)
void flash_attn(const bf16_t* __restrict__ Qb, const bf16_t* __restrict__ Kb,
                const bf16_t* __restrict__ Vt, bf16_t* __restrict__ Ob) {
  __shared__ __align__(16) bf16_t Ks[2][64 * 128];   // (key, d), swizzle grp^(row&15)
  __shared__ __align__(16) bf16_t Vs[2][128 * 64];   // (d, key), swizzle grp^(row&7)
  __shared__ __align__(16) bf16_t Ps[4][16 * 72];    // wave-private P^T: [q][key], +8 pad

  const int tid = threadIdx.x;
  const int wave = tid >> 6, lane = tid & 63;
  const int quad = lane >> 4, l16 = lane & 15;
  const int nQT = T_ / 64;             // 32
  const int bid = blockIdx.x;
  const int j  = bid & 15;             // q-tile pair index
  const int bh = bid >> 4;             // (b, h)
  const int h = bh % NH_;
  const int b = bh / NH_;
  const int kv = h >> 2;               // GQA: n_rep = 4
  const int qta = j, qtb = (nQT - 1) - j;   // qta < qtb always

  const bf16_t* kbase = Kb + ((size_t)(b * NKV_ + kv) * T_) * HD_;
  const bf16_t* vbase = Vt + ((size_t)(b * NKV_ + kv) * HD_) * T_;

  // hoisted staging source pointers (advance by stride per kt)
  const bf16_t* kptr[4];
  const bf16_t* vptr[4];
#pragma unroll
  for (int i = 0; i < 4; i++) {
    int e = i * 256 + tid;
    { int row = e >> 4, grp = e & 15; int gg = grp ^ (row & 15);
      kptr[i] = kbase + (size_t)row * HD_ + gg * 8; }
    { int row = e >> 3, grp = e & 7;  int gg = grp ^ (row & 7);
      vptr[i] = vbase + (size_t)row * T_ + gg * 8; }
  }

  auto stage = [&](int bufi) {
#pragma unroll
    for (int i = 0; i < 4; i++) {
      async_copy16(kptr[i], &Ks[bufi][(i * 256 + tid) * 8]);
      kptr[i] += 64 * HD_;
    }
#pragma unroll
    for (int i = 0; i < 4; i++) {
      async_copy16(vptr[i], &Vs[bufi][(i * 256 + tid) * 8]);
      vptr[i] += 64;
    }
  };

  stage(0);  // prefetch first tile

  // Q fragments (B-operand): lane n=l16 -> q row, holds d = ks*32+quad*8+j
  // index 0 -> q-tile a, index 1 -> q-tile b
  bf16x8 qf[2][4];
#pragma unroll
  for (int x = 0; x < 2; x++) {
    int qt = x ? qtb : qta;
    const bf16_t* qptr =
        Qb + ((size_t)(b * NH_ + h) * T_ + qt * 64 + wave * 16 + l16) * HD_;
#pragma unroll
    for (int ks = 0; ks < 4; ks++)
      qf[x][ks] = *(const bf16x8*)(qptr + ks * 32 + quad * 8);
  }

  // O^T accumulators: o[x][dt][r] = O^T[d = dt*16+quad*4+r][q = l16]
  floatx4 o[2][8];
#pragma unroll
  for (int x = 0; x < 2; x++)
#pragma unroll
    for (int i = 0; i < 8; i++) o[x][i] = floatx4{0.f, 0.f, 0.f, 0.f};
  float m_s[2] = {-1e30f, -1e30f};
  float l_s[2] = {0.f, 0.f};

  // softmax (exp2 domain) + P^T->LDS + PV for one q-tile's S^T
  auto softmax_pv = [&](floatx4 (&s)[4], int x, bool diag, int bufi) {
    if (diag) {
      int qlocal = wave * 16 + l16;
#pragma unroll
      for (int nt = 0; nt < 4; nt++)
#pragma unroll
        for (int r = 0; r < 4; r++) {
          int klocal = nt * 16 + quad * 4 + r;
          if (klocal > qlocal) s[nt][r] = -1e30f;
        }
    }
    float mx = fmaxf(fmaxf(s[0][0], s[0][1]), fmaxf(s[0][2], s[0][3]));
#pragma unroll
    for (int nt = 1; nt < 4; nt++)
      mx = fmaxf(mx, fmaxf(fmaxf(s[nt][0], s[nt][1]), fmaxf(s[nt][2], s[nt][3])));
    mx = fmaxf(mx, __shfl_xor(mx, 16, 64));
    mx = fmaxf(mx, __shfl_xor(mx, 32, 64));
    float mold = m_s[x];
    float mnew = fmaxf(mold, mx);
    m_s[x] = mnew;
    float sum = 0.f;
#pragma unroll
    for (int nt = 0; nt < 4; nt++)
#pragma unroll
      for (int r = 0; r < 4; r++) {
        float p = __builtin_amdgcn_exp2f(s[nt][r] - mnew);
        s[nt][r] = p;
        sum += p;
      }
    sum += __shfl_xor(sum, 16, 64);
    sum += __shfl_xor(sum, 32, 64);
    if (__any(mnew > mold)) {
      float alpha = __builtin_amdgcn_exp2f(mold - mnew);
      l_s[x] = l_s[x] * alpha + sum;
#pragma unroll
      for (int dt = 0; dt < 8; dt++) o[x][dt] *= alpha;
    } else {
      l_s[x] += sum;
    }
    // P^T -> LDS: row q=l16, keys nt*16+quad*4..+3 as one 8B write
#pragma unroll
    for (int nt = 0; nt < 4; nt++) {
      bf16x4 p4;
#pragma unroll
      for (int r = 0; r < 4; r++) p4[r] = (bf16_t)s[nt][r];
      *(bf16x4*)(&Ps[wave][l16 * 72 + nt * 16 + quad * 4]) = p4;
    }
    // O^T += V^T P^T (wave-private Ps: in-order DS, no barrier needed)
#pragma unroll
    for (int ks = 0; ks < 2; ks++) {
      bf16x8 pf = *(const bf16x8*)(&Ps[wave][l16 * 72 + ks * 32 + quad * 8]);
      int grp = ks * 4 + quad;
#pragma unroll
      for (int dt = 0; dt < 8; dt++) {
        int row = dt * 16 + l16;
        bf16x8 vf = *(const bf16x8*)(&Vs[bufi][row * 64 + ((grp ^ (row & 7)) << 3)]);
        o[x][dt] = __builtin_amdgcn_mfma_f32_16x16x32_bf16(vf, pf, o[x][dt], 0, 0, 0);
      }
    }
  };

  for (int kt = 0; kt <= qtb; kt++) {
    const int bufi = kt & 1;
    // barrier: drains vmcnt (staging of THIS tile, issued last iter, is done)
    // and protects the buffer we are about to overwrite.
    __syncthreads();
    if (kt < qtb) stage(bufi ^ 1);  // prefetch next tile (other buffer)

    if (kt <= qta) {
      // overlap phase: both q-tiles active; kf loaded ONCE, used twice
      floatx4 s[2][4];
#pragma unroll
      for (int x = 0; x < 2; x++)
#pragma unroll
        for (int nt = 0; nt < 4; nt++) s[x][nt] = floatx4{0.f, 0.f, 0.f, 0.f};
#pragma unroll
      for (int ks = 0; ks < 4; ks++) {
        int grp = ks * 4 + quad;
#pragma unroll
        for (int nt = 0; nt < 4; nt++) {
          int row = nt * 16 + l16;
          bf16x8 kf = *(const bf16x8*)(&Ks[bufi][row * 128 + ((grp ^ (row & 15)) << 3)]);
          s[0][nt] = __builtin_amdgcn_mfma_f32_16x16x32_bf16(kf, qf[0][ks], s[0][nt], 0, 0, 0);
          s[1][nt] = __builtin_amdgcn_mfma_f32_16x16x32_bf16(kf, qf[1][ks], s[1][nt], 0, 0, 0);
        }
      }
      softmax_pv(s[0], 0, kt == qta, bufi);
      softmax_pv(s[1], 1, false, bufi);       // qtb > qta >= kt: no diag here
    } else {
      // single phase: only q-tile b
      floatx4 s[4];
#pragma unroll
      for (int nt = 0; nt < 4; nt++) s[nt] = floatx4{0.f, 0.f, 0.f, 0.f};
#pragma unroll
      for (int ks = 0; ks < 4; ks++) {
        int grp = ks * 4 + quad;
#pragma unroll
        for (int nt = 0; nt < 4; nt++) {
          int row = nt * 16 + l16;
          bf16x8 kf = *(const bf16x8*)(&Ks[bufi][row * 128 + ((grp ^ (row & 15)) << 3)]);
          s[nt] = __builtin_amdgcn_mfma_f32_16x16x32_bf16(kf, qf[1][ks], s[nt], 0, 0, 0);
        }
      }
      softmax_pv(s, 1, kt == qtb, bufi);
    }
  }

  // epilogue: lane owns q-row qg; d = dt*16+quad*4+r, packed 8B stores
#pragma unroll
  for (int x = 0; x < 2; x++) {
    int qt = x ? qtb : qta;
    int qg = qt * 64 + wave * 16 + l16;
    float inv_l = 1.f / l_s[x];
    size_t base = ((size_t)(b * T_) + qg) * D_ + h * HD_;
#pragma unroll
    for (int dt = 0; dt < 8; dt++) {
      bf16x4 w;
#pragma unroll
      for (int r = 0; r < 4; r++) w[r] = (bf16_t)(o[x][dt][r] * inv_l);
      *(bf16x4*)(Ob + base + dt * 16 + quad * 4) = w;
    }
  }
}

// ---------------------------------------------------------------------------
extern "C" void kernel_launch(void* const* d_in, const int* in_sizes, int n_in,
                              void* d_out, int out_size, void* d_ws, size_t ws_size,
                              hipStream_t stream) {
  const float* x  = (const float*)d_in[0];
  const float* wq = (const float*)d_in[1];
  const float* wk = (const float*)d_in[2];
  const float* wv = (const float*)d_in[3];
  const float* wo = (const float*)d_in[4];
  float* out = (float*)d_out;

  // workspace layout (bf16 elems); attn output aliases x_bf (x_bf dead after GEMM1)
  bf16_t* x_bf   = (bf16_t*)d_ws;                          // 4096*2048
  bf16_t* attn_o = x_bf;                                   // alias
  bf16_t* wqkv_t = x_bf + (size_t)MROWS * D_;              // 3072*2048
  bf16_t* wo_t   = wqkv_t + (size_t)NQKV * D_;             // 2048*2048
  bf16_t* qkv    = wo_t + (size_t)D_ * D_;                 // 4096*3072
  bf16_t* Qb     = qkv + (size_t)MROWS * NQKV;             // 2*16*2048*128
  bf16_t* Kb     = Qb + (size_t)B_ * NH_ * T_ * HD_;       // 2*4*2048*128
  bf16_t* Vt     = Kb + (size_t)B_ * NKV_ * T_ * HD_;      // 2*4*128*2048

  // 1. casts / weight transposes
  cast_f32_bf16<<<(MROWS * D_) / (256 * 8), 256, 0, stream>>>(x, x_bf, MROWS * D_);
  transpose_cast<<<dim3(64, 64), dim3(32, 8), 0, stream>>>(wq, wqkv_t, D_, 2048);
  transpose_cast<<<dim3(16, 64), dim3(32, 8), 0, stream>>>(wk, wqkv_t + (size_t)2048 * D_, D_, 512);
  transpose_cast<<<dim3(16, 64), dim3(32, 8), 0, stream>>>(wv, wqkv_t + (size_t)2560 * D_, D_, 512);
  transpose_cast<<<dim3(64, 64), dim3(32, 8), 0, stream>>>(wo, wo_t, D_, 2048);

  // 2. fused QKV projection: (4096,2048) x (2048,3072) -> bf16
  gemm_bt<bf16_t><<<(MROWS / 128) * (NQKV / 128), 256, 0, stream>>>(
      x_bf, wqkv_t, qkv, MROWS, NQKV, D_);

  // 3. RoPE + GQA scatter + V transpose
  rope_scatter<<<(MROWS * (NH_ + NKV_) * 64) / 256, 256, 0, stream>>>(qkv, Qb, Kb);
  v_transpose<<<dim3(T_ / 32, HD_ / 32, B_ * NKV_), dim3(32, 8), 0, stream>>>(qkv, Vt);

  // 4. causal flash attention: complementary q-tile pairing, 512 uniform blocks
  flash_attn<<<B_ * NH_ * (T_ / 128), 256, 0, stream>>>(Qb, Kb, Vt, attn_o);

  // 5. output projection: (4096,2048) x (2048,2048) -> fp32
  gemm_bt<float><<<(MROWS / 128) * (D_ / 128), 256, 0, stream>>>(
      attn_o, wo_t, out, MROWS, D_, D_);
}

// Round 7
// 281.661 us; speedup vs baseline: 1.1482x; 1.1482x over previous
//
#include <hip/hip_runtime.h>
#include <hip/hip_bf16.h>
#include <math.h>

// Problem constants
#define B_   2
#define T_   2048
#define D_   2048
#define NH_  16
#define NKV_ 4
#define HD_  128
#define MROWS (B_*T_)          // 4096
#define NQKV  (NH_*HD_ + 2*NKV_*HD_)  // 3072

typedef __bf16 bf16_t;
typedef __bf16 bf16x8 __attribute__((ext_vector_type(8)));
typedef __bf16 bf16x4 __attribute__((ext_vector_type(4)));
typedef float  floatx4 __attribute__((ext_vector_type(4)));

// ---------------------------------------------------------------------------
// async global->LDS, 16B per lane. LDS dest must be wave-uniform base + lane*16.
__device__ __forceinline__ void async_copy16(const bf16_t* gsrc, bf16_t* ldst) {
  __builtin_amdgcn_global_load_lds(
      (const __attribute__((address_space(1))) unsigned int*)gsrc,
      (__attribute__((address_space(3))) unsigned int*)ldst, 16, 0, 0);
}

// ---------------------------------------------------------------------------
// cast fp32 -> bf16, 8 elems/thread
__global__ void cast_f32_bf16(const float* __restrict__ src, bf16_t* __restrict__ dst, int n) {
  int i = (blockIdx.x * 256 + threadIdx.x) * 8;
  if (i >= n) return;
  float4 a = *(const float4*)(src + i);
  float4 b = *(const float4*)(src + i + 4);
  bf16x8 v;
  v[0]=(bf16_t)a.x; v[1]=(bf16_t)a.y; v[2]=(bf16_t)a.z; v[3]=(bf16_t)a.w;
  v[4]=(bf16_t)b.x; v[5]=(bf16_t)b.y; v[6]=(bf16_t)b.z; v[7]=(bf16_t)b.w;
  *(bf16x8*)(dst + i) = v;
}

// ---------------------------------------------------------------------------
// Fused transpose+cast for all 4 weights in ONE dispatch (z picks the matrix).
// src (K,N) fp32 row-major -> dst (N,K) bf16 row-major. K=2048 for all;
// N=2048 for wq/wo, 512 for wk/wv. Idle blocks (n0>=N) exit immediately.
// grid (64, 64, 4), block (32,8)
__global__ void transpose_cast4(const float* __restrict__ s0, const float* __restrict__ s1,
                                const float* __restrict__ s2, const float* __restrict__ s3,
                                bf16_t* __restrict__ d0, bf16_t* __restrict__ d1,
                                bf16_t* __restrict__ d2, bf16_t* __restrict__ d3) {
  const int z = blockIdx.z;
  const int N = (z == 1 || z == 2) ? 512 : 2048;
  const int n0 = blockIdx.x * 32;
  if (n0 >= N) return;
  const float* src = (z == 0) ? s0 : (z == 1) ? s1 : (z == 2) ? s2 : s3;
  bf16_t*      dst = (z == 0) ? d0 : (z == 1) ? d1 : (z == 2) ? d2 : d3;
  const int K = 2048;
  __shared__ float tile[32][33];
  int k0 = blockIdx.y * 32;
  int tx = threadIdx.x, ty = threadIdx.y;
#pragma unroll
  for (int r = 0; r < 4; r++)
    tile[ty + r*8][tx] = src[(size_t)(k0 + ty + r*8) * N + n0 + tx];
  __syncthreads();
#pragma unroll
  for (int r = 0; r < 4; r++)
    dst[(size_t)(n0 + ty + r*8) * K + k0 + tx] = (bf16_t)tile[tx][ty + r*8];
}

// ---------------------------------------------------------------------------
// C(M,N) = A(M,K) * Bt(N,K)^T   all bf16 in, OUT_T out.
// 128x128 tile, BK=64, 4 waves (2x2 of 64x64), 16x16x32 MFMA.
template <typename OUT_T>
__global__ __launch_bounds__(256, 2)
void gemm_bt(const bf16_t* __restrict__ A, const bf16_t* __restrict__ Bt,
             OUT_T* __restrict__ C, int M, int N, int K) {
  __shared__ __align__(16) bf16_t As[128 * 64];
  __shared__ __align__(16) bf16_t Bs[128 * 64];
  const int tid  = threadIdx.x;
  const int wave = tid >> 6, lane = tid & 63;
  const int quad = lane >> 4, l16 = lane & 15;
  const int nBlocksM = M >> 7;
  const int bm = blockIdx.x % nBlocksM, bn = blockIdx.x / nBlocksM;
  const int m0 = bm * 128, n0 = bn * 128;
  const int wm = (wave >> 1) * 64, wn = (wave & 1) * 64;

  floatx4 acc[4][4];
#pragma unroll
  for (int i = 0; i < 4; i++)
#pragma unroll
    for (int j = 0; j < 4; j++) acc[i][j] = floatx4{0.f, 0.f, 0.f, 0.f};

  for (int k0 = 0; k0 < K; k0 += 64) {
    __syncthreads();
#pragma unroll
    for (int i = 0; i < 4; i++) {
      int e = i * 256 + tid;
      int row = e >> 3, grp = e & 7;
      int gg = grp ^ (row & 7);
      async_copy16(A + (size_t)(m0 + row) * K + k0 + gg * 8, As + e * 8);
    }
#pragma unroll
    for (int i = 0; i < 4; i++) {
      int e = i * 256 + tid;
      int row = e >> 3, grp = e & 7;
      int gg = grp ^ (row & 7);
      async_copy16(Bt + (size_t)(n0 + row) * K + k0 + gg * 8, Bs + e * 8);
    }
    __syncthreads();
#pragma unroll
    for (int ks = 0; ks < 2; ks++) {
      bf16x8 af[4], bfr[4];
      int grp = ks * 4 + quad;
#pragma unroll
      for (int mi = 0; mi < 4; mi++) {
        int row = wm + mi * 16 + l16;
        af[mi] = *(const bf16x8*)(As + row * 64 + ((grp ^ (row & 7)) << 3));
      }
#pragma unroll
      for (int ni = 0; ni < 4; ni++) {
        int row = wn + ni * 16 + l16;
        bfr[ni] = *(const bf16x8*)(Bs + row * 64 + ((grp ^ (row & 7)) << 3));
      }
#pragma unroll
      for (int mi = 0; mi < 4; mi++)
#pragma unroll
        for (int ni = 0; ni < 4; ni++)
          acc[mi][ni] = __builtin_amdgcn_mfma_f32_16x16x32_bf16(af[mi], bfr[ni], acc[mi][ni], 0, 0, 0);
    }
  }
  // epilogue: C row = quad*4+reg (+16*mi), col = lane&15 (+16*ni)  [m89/m91 layout]
#pragma unroll
  for (int mi = 0; mi < 4; mi++) {
#pragma unroll
    for (int r = 0; r < 4; r++) {
      int row = m0 + wm + mi * 16 + quad * 4 + r;
      size_t base = (size_t)row * N + n0 + wn;
#pragma unroll
      for (int ni = 0; ni < 4; ni++)
        C[base + ni * 16 + l16] = (OUT_T)acc[mi][ni][r];
    }
  }
}

// ---------------------------------------------------------------------------
// RoPE + scatter: qkv (4096, 3072) bf16 -> Qb (B,NH,T,HD) scaled+roped,
//                 Kb (B,NKV,T,HD) roped.  One thread per (row, head, j<64).
// Q scale = 1/sqrt(128) * log2(e)  (flash softmax runs in exp2 domain)
// Fast-math trig: __expf / __sincosf (v_exp_f32 / v_sin_f32 class, ~10 cy)
__global__ void rope_scatter(const bf16_t* __restrict__ qkv,
                             bf16_t* __restrict__ Qb, bf16_t* __restrict__ Kb) {
  int g = blockIdx.x * 256 + threadIdx.x;
  int j = g & 63;
  int rest = g >> 6;
  int head = rest % (NH_ + NKV_);
  int row  = rest / (NH_ + NKV_);     // b*T + t
  int t = row & (T_ - 1);
  int b = row >> 11;                  // T_ = 2048
  const bf16_t* src = qkv + (size_t)row * NQKV;
  // inv_freq = 10000^(-j/64) = exp(-j * ln(10000)/64)
  float ang = (float)t * __expf(-0.14391156816f * (float)j);
  float sn, cs;
  __sincosf(ang, &sn, &cs);
  if (head < NH_) {
    float x0 = (float)src[head * HD_ + j];
    float x1 = (float)src[head * HD_ + 64 + j];
    const float scale = 0.12751651541057752f;  // 1/sqrt(128)*log2(e)
    bf16_t* dst = Qb + ((size_t)(b * NH_ + head) * T_ + t) * HD_;
    dst[j]      = (bf16_t)((x0 * cs - x1 * sn) * scale);
    dst[j + 64] = (bf16_t)((x1 * cs + x0 * sn) * scale);
  } else {
    int kvh = head - NH_;
    float x0 = (float)src[NH_ * HD_ + kvh * HD_ + j];
    float x1 = (float)src[NH_ * HD_ + kvh * HD_ + 64 + j];
    bf16_t* dst = Kb + ((size_t)(b * NKV_ + kvh) * T_ + t) * HD_;
    dst[j]      = (bf16_t)(x0 * cs - x1 * sn);
    dst[j + 64] = (bf16_t)(x1 * cs + x0 * sn);
  }
}

// ---------------------------------------------------------------------------
// V transpose: qkv V-slice (b,t,kv,d) -> Vt (B,NKV,HD,T)
__global__ void v_transpose(const bf16_t* __restrict__ qkv, bf16_t* __restrict__ Vt) {
  __shared__ float tile[32][33];
  int t0 = blockIdx.x * 32, d0 = blockIdx.y * 32;
  int bk = blockIdx.z;
  int b = bk / NKV_, kvh = bk % NKV_;
  int tx = threadIdx.x, ty = threadIdx.y;
#pragma unroll
  for (int r = 0; r < 4; r++) {
    int t = t0 + ty + r * 8;
    tile[ty + r*8][tx] =
        (float)qkv[(size_t)(b * T_ + t) * NQKV + (NH_ + NKV_) * HD_ + kvh * HD_ + d0 + tx];
  }
  __syncthreads();
#pragma unroll
  for (int r = 0; r < 4; r++) {
    int d = d0 + ty + r * 8;
    Vt[((size_t)(b * NKV_ + kvh) * HD_ + d) * T_ + t0 + tx] = (bf16_t)tile[tx][ty + r*8];
  }
}

// ---------------------------------------------------------------------------
// Flash attention v4 (the measured-best shape): S^T formulation.
// mfma(kf, qf) -> S^T = K Q^T: each lane's 16 S-values all belong to ONE q-row
// (col = l16), so softmax row-reductions are 15 in-lane ops + 2 shuffles.
// P^T -> LDS as 4x 8B writes; PV computes O^T = V^T P^T with Vs (d,key) as
// the A-operand. BQ=64/block, BK=64, double-buffered K/V staging,
// heavy-first order, exp2-domain softmax (scale*log2e folded into Q).
// NOTE: register sweet spot — 88 VGPR, zero spill at 2 blocks/CU. Doubling
// per-block work (2 heads or 2 q-tiles) spills or kills occupancy (R5/R6).
__global__ __launch_bounds__(256, 2)
void flash_attn(const bf16_t* __restrict__ Qb, const bf16_t* __restrict__ Kb,
                const bf16_t* __restrict__ Vt, bf16_t* __restrict__ Ob) {
  __shared__ __align__(16) bf16_t Ks[2][64 * 128];   // (key, d), swizzle grp^(row&15)
  __shared__ __align__(16) bf16_t Vs[2][128 * 64];   // (d, key), swizzle grp^(row&7)
  __shared__ __align__(16) bf16_t Ps[4][16 * 72];    // wave-private P^T: [q][key], +8 pad

  const int tid = threadIdx.x;
  const int wave = tid >> 6, lane = tid & 63;
  const int quad = lane >> 4, l16 = lane & 15;
  const int nQT = T_ / 64;  // 32
  const int bid = blockIdx.x;
  const int bh = bid % (B_ * NH_);
  const int qt = (nQT - 1) - (bid / (B_ * NH_));   // heavy-first
  const int h = bh % NH_;
  const int b = bh / NH_;
  const int kv = h >> 2;    // GQA: n_rep = 4

  const bf16_t* qbase = Qb + ((size_t)(b * NH_ + h) * T_ + qt * 64) * HD_;
  const bf16_t* kbase = Kb + ((size_t)(b * NKV_ + kv) * T_) * HD_;
  const bf16_t* vbase = Vt + ((size_t)(b * NKV_ + kv) * HD_) * T_;

  // stage key tile kt into buffer bufi (K: 64 keys x 128 d; V^T: 128 d x 64 keys)
  auto stage = [&](int kt, int bufi) {
#pragma unroll
    for (int i = 0; i < 4; i++) {
      int e = i * 256 + tid;
      int row = e >> 4, grp = e & 15;
      int gg = grp ^ (row & 15);
      async_copy16(kbase + (size_t)(kt * 64 + row) * HD_ + gg * 8, &Ks[bufi][e * 8]);
    }
#pragma unroll
    for (int i = 0; i < 4; i++) {
      int e = i * 256 + tid;
      int row = e >> 3, grp = e & 7;
      int gg = grp ^ (row & 7);
      async_copy16(vbase + (size_t)row * T_ + kt * 64 + gg * 8, &Vs[bufi][e * 8]);
    }
  };

  stage(0, 0);  // prefetch first tile before anything else

  // Q fragments (B-operand; same register layout as A): lane n=l16 -> q row,
  // holds d = ks*32 + quad*8 + j.
  bf16x8 qf[4];
  {
    const bf16_t* qptr = qbase + (wave * 16 + l16) * HD_;
#pragma unroll
    for (int ks = 0; ks < 4; ks++)
      qf[ks] = *(const bf16x8*)(qptr + ks * 32 + quad * 8);
  }

  // O^T accumulators: o[dt][r] = O^T[d = dt*16+quad*4+r][q = l16]
  floatx4 o[8];
#pragma unroll
  for (int i = 0; i < 8; i++) o[i] = floatx4{0.f, 0.f, 0.f, 0.f};
  float m_s = -1e30f, l_s = 0.f;  // per-lane: this lane's q-row state

  for (int kt = 0; kt <= qt; kt++) {
    const int bufi = kt & 1;
    // barrier: (a) drains vmcnt -> staging of THIS tile (issued last iter) done;
    // (b) all waves finished compute on the buffer we are about to overwrite.
    __syncthreads();
    if (kt < qt) stage(kt + 1, bufi ^ 1);  // prefetch next tile (other buffer)

    // S^T = K Q^T : s[nt][r] = S^T[key = nt*16+quad*4+r][q = l16]
    floatx4 s[4];
#pragma unroll
    for (int nt = 0; nt < 4; nt++) s[nt] = floatx4{0.f, 0.f, 0.f, 0.f};
#pragma unroll
    for (int ks = 0; ks < 4; ks++) {
      int grp = ks * 4 + quad;
#pragma unroll
      for (int nt = 0; nt < 4; nt++) {
        int row = nt * 16 + l16;
        bf16x8 kf = *(const bf16x8*)(&Ks[bufi][row * 128 + ((grp ^ (row & 15)) << 3)]);
        s[nt] = __builtin_amdgcn_mfma_f32_16x16x32_bf16(kf, qf[ks], s[nt], 0, 0, 0);
      }
    }

    // causal mask (only the diagonal tile needs it): key_local > q_local
    if (kt == qt) {
      int qlocal = wave * 16 + l16;
#pragma unroll
      for (int nt = 0; nt < 4; nt++)
#pragma unroll
        for (int r = 0; r < 4; r++) {
          int klocal = nt * 16 + quad * 4 + r;
          if (klocal > qlocal) s[nt][r] = -1e30f;
        }
    }

    // online softmax, exp2 domain. All 16 values in this lane share one q-row;
    // full 64-key reduction = in-lane tree + 2 cross-quad shuffles.
    float mx = fmaxf(fmaxf(s[0][0], s[0][1]), fmaxf(s[0][2], s[0][3]));
#pragma unroll
    for (int nt = 1; nt < 4; nt++)
      mx = fmaxf(mx, fmaxf(fmaxf(s[nt][0], s[nt][1]), fmaxf(s[nt][2], s[nt][3])));
    mx = fmaxf(mx, __shfl_xor(mx, 16, 64));
    mx = fmaxf(mx, __shfl_xor(mx, 32, 64));
    float mnew = fmaxf(m_s, mx);
    float alpha = __builtin_amdgcn_exp2f(m_s - mnew);
    m_s = mnew;
    float sum = 0.f;
#pragma unroll
    for (int nt = 0; nt < 4; nt++)
#pragma unroll
      for (int r = 0; r < 4; r++) {
        float p = __builtin_amdgcn_exp2f(s[nt][r] - mnew);
        s[nt][r] = p;
        sum += p;
      }
    sum += __shfl_xor(sum, 16, 64);
    sum += __shfl_xor(sum, 32, 64);
    l_s = l_s * alpha + sum;
#pragma unroll
    for (int dt = 0; dt < 8; dt++) o[dt] *= alpha;

    // P^T -> LDS: row q=l16, keys nt*16+quad*4..+3 packed as one 8B write
#pragma unroll
    for (int nt = 0; nt < 4; nt++) {
      bf16x4 p4;
#pragma unroll
      for (int r = 0; r < 4; r++) p4[r] = (bf16_t)s[nt][r];
      *(bf16x4*)(&Ps[wave][l16 * 72 + nt * 16 + quad * 4]) = p4;
    }

    // O^T += V^T P^T : A = Vs (d,key) as stored; B = P^T rows (8 keys/lane)
#pragma unroll
    for (int ks = 0; ks < 2; ks++) {
      bf16x8 pf = *(const bf16x8*)(&Ps[wave][l16 * 72 + ks * 32 + quad * 8]);
      int grp = ks * 4 + quad;
#pragma unroll
      for (int dt = 0; dt < 8; dt++) {
        int row = dt * 16 + l16;
        bf16x8 vf = *(const bf16x8*)(&Vs[bufi][row * 64 + ((grp ^ (row & 7)) << 3)]);
        o[dt] = __builtin_amdgcn_mfma_f32_16x16x32_bf16(vf, pf, o[dt], 0, 0, 0);
      }
    }
  }

  // epilogue: lane owns q-row qg = wrow0 + l16; d = dt*16+quad*4+r.
  // Pack 4 consecutive d as 8B stores.
  {
    int qg = qt * 64 + wave * 16 + l16;
    float inv_l = 1.f / l_s;
    size_t base = ((size_t)(b * T_) + qg) * D_ + h * HD_;
#pragma unroll
    for (int dt = 0; dt < 8; dt++) {
      bf16x4 w;
#pragma unroll
      for (int r = 0; r < 4; r++) w[r] = (bf16_t)(o[dt][r] * inv_l);
      *(bf16x4*)(Ob + base + dt * 16 + quad * 4) = w;
    }
  }
}

// ---------------------------------------------------------------------------
extern "C" void kernel_launch(void* const* d_in, const int* in_sizes, int n_in,
                              void* d_out, int out_size, void* d_ws, size_t ws_size,
                              hipStream_t stream) {
  const float* x  = (const float*)d_in[0];
  const float* wq = (const float*)d_in[1];
  const float* wk = (const float*)d_in[2];
  const float* wv = (const float*)d_in[3];
  const float* wo = (const float*)d_in[4];
  float* out = (float*)d_out;

  // workspace layout (bf16 elems); attn output aliases x_bf (x_bf dead after GEMM1)
  bf16_t* x_bf   = (bf16_t*)d_ws;                          // 4096*2048
  bf16_t* attn_o = x_bf;                                   // alias
  bf16_t* wqkv_t = x_bf + (size_t)MROWS * D_;              // 3072*2048
  bf16_t* wo_t   = wqkv_t + (size_t)NQKV * D_;             // 2048*2048
  bf16_t* qkv    = wo_t + (size_t)D_ * D_;                 // 4096*3072
  bf16_t* Qb     = qkv + (size_t)MROWS * NQKV;             // 2*16*2048*128
  bf16_t* Kb     = Qb + (size_t)B_ * NH_ * T_ * HD_;       // 2*4*2048*128
  bf16_t* Vt     = Kb + (size_t)B_ * NKV_ * T_ * HD_;      // 2*4*128*2048

  // 1. casts / weight transposes (one fused dispatch for all 4 weights)
  cast_f32_bf16<<<(MROWS * D_) / (256 * 8), 256, 0, stream>>>(x, x_bf, MROWS * D_);
  transpose_cast4<<<dim3(64, 64, 4), dim3(32, 8), 0, stream>>>(
      wq, wk, wv, wo,
      wqkv_t, wqkv_t + (size_t)2048 * D_, wqkv_t + (size_t)2560 * D_, wo_t);

  // 2. fused QKV projection: (4096,2048) x (2048,3072) -> bf16
  gemm_bt<bf16_t><<<(MROWS / 128) * (NQKV / 128), 256, 0, stream>>>(
      x_bf, wqkv_t, qkv, MROWS, NQKV, D_);

  // 3. RoPE + GQA scatter + V transpose
  rope_scatter<<<(MROWS * (NH_ + NKV_) * 64) / 256, 256, 0, stream>>>(qkv, Qb, Kb);
  v_transpose<<<dim3(T_ / 32, HD_ / 32, B_ * NKV_), dim3(32, 8), 0, stream>>>(qkv, Vt);

  // 4. causal flash attention: v4 (BQ=64, double-buffered, heavy-first)
  flash_attn<<<B_ * NH_ * (T_ / 64), 256, 0, stream>>>(Qb, Kb, Vt, attn_o);

  // 5. output projection: (4096,2048) x (2048,2048) -> fp32
  gemm_bt<float><<<(MROWS / 128) * (D_ / 128), 256, 0, stream>>>(
      attn_o, wo_t, out, MROWS, D_, D_);
}

// Round 8
// 264.701 us; speedup vs baseline: 1.2218x; 1.0641x over previous
//
#include <hip/hip_runtime.h>
#include <hip/hip_bf16.h>
#include <math.h>

// Problem constants
#define B_   2
#define T_   2048
#define D_   2048
#define NH_  16
#define NKV_ 4
#define HD_  128
#define MROWS (B_*T_)          // 4096
#define NQKV  (NH_*HD_ + 2*NKV_*HD_)  // 3072

typedef __bf16 bf16_t;
typedef __bf16 bf16x8 __attribute__((ext_vector_type(8)));
typedef __bf16 bf16x4 __attribute__((ext_vector_type(4)));
typedef float  floatx4 __attribute__((ext_vector_type(4)));

// ---------------------------------------------------------------------------
// async global->LDS, 16B per lane. LDS dest must be wave-uniform base + lane*16.
__device__ __forceinline__ void async_copy16(const bf16_t* gsrc, bf16_t* ldst) {
  __builtin_amdgcn_global_load_lds(
      (const __attribute__((address_space(1))) unsigned int*)gsrc,
      (__attribute__((address_space(3))) unsigned int*)ldst, 16, 0, 0);
}

// ---------------------------------------------------------------------------
// Fused prep: z=0..3 -> transpose+cast weight z; z=4 -> elementwise cast of x.
// Weights: src (K,N) fp32 row-major -> dst (N,K) bf16 row-major, K=2048;
// N=2048 for wq/wo, 512 for wk/wv (idle blocks exit). x: 8M elems, 2048/block.
// grid (64, 64, 5), block (32,8)
__global__ void prep_fused(const float* __restrict__ s0, const float* __restrict__ s1,
                           const float* __restrict__ s2, const float* __restrict__ s3,
                           const float* __restrict__ sx,
                           bf16_t* __restrict__ d0, bf16_t* __restrict__ d1,
                           bf16_t* __restrict__ d2, bf16_t* __restrict__ d3,
                           bf16_t* __restrict__ dx) {
  const int z = blockIdx.z;
  const int tx = threadIdx.x, ty = threadIdx.y;
  if (z == 4) {
    // cast x -> bf16, 8 elems/thread, 2048 elems/block
    int i = ((blockIdx.y * 64 + blockIdx.x) * 256 + ty * 32 + tx) * 8;
    float4 a = *(const float4*)(sx + i);
    float4 b = *(const float4*)(sx + i + 4);
    bf16x8 v;
    v[0]=(bf16_t)a.x; v[1]=(bf16_t)a.y; v[2]=(bf16_t)a.z; v[3]=(bf16_t)a.w;
    v[4]=(bf16_t)b.x; v[5]=(bf16_t)b.y; v[6]=(bf16_t)b.z; v[7]=(bf16_t)b.w;
    *(bf16x8*)(dx + i) = v;
    return;
  }
  const int N = (z == 1 || z == 2) ? 512 : 2048;
  const int n0 = blockIdx.x * 32;
  if (n0 >= N) return;
  const float* src = (z == 0) ? s0 : (z == 1) ? s1 : (z == 2) ? s2 : s3;
  bf16_t*      dst = (z == 0) ? d0 : (z == 1) ? d1 : (z == 2) ? d2 : d3;
  const int K = 2048;
  __shared__ float tile[32][33];
  int k0 = blockIdx.y * 32;
#pragma unroll
  for (int r = 0; r < 4; r++)
    tile[ty + r*8][tx] = src[(size_t)(k0 + ty + r*8) * N + n0 + tx];
  __syncthreads();
#pragma unroll
  for (int r = 0; r < 4; r++)
    dst[(size_t)(n0 + ty + r*8) * K + k0 + tx] = (bf16_t)tile[tx][ty + r*8];
}

// ---------------------------------------------------------------------------
// C(M,N) = A(M,K) * Bt(N,K)^T   all bf16 in, OUT_T out.
// 128x128 tile, BK=64, 4 waves (2x2 of 64x64), 16x16x32 MFMA.
// launch_bounds (256,3): cap VGPR ~170 so 3 blocks/CU co-reside (m97 config:
// 164 VGPR -> 3 blk/CU is part of its 874 TF). GEMM1's 768 blocks then fit
// in ONE resident round (3*256=768 slots).
template <typename OUT_T>
__global__ __launch_bounds__(256, 3)
void gemm_bt(const bf16_t* __restrict__ A, const bf16_t* __restrict__ Bt,
             OUT_T* __restrict__ C, int M, int N, int K) {
  __shared__ __align__(16) bf16_t As[128 * 64];
  __shared__ __align__(16) bf16_t Bs[128 * 64];
  const int tid  = threadIdx.x;
  const int wave = tid >> 6, lane = tid & 63;
  const int quad = lane >> 4, l16 = lane & 15;
  const int nBlocksM = M >> 7;
  const int bm = blockIdx.x % nBlocksM, bn = blockIdx.x / nBlocksM;
  const int m0 = bm * 128, n0 = bn * 128;
  const int wm = (wave >> 1) * 64, wn = (wave & 1) * 64;

  floatx4 acc[4][4];
#pragma unroll
  for (int i = 0; i < 4; i++)
#pragma unroll
    for (int j = 0; j < 4; j++) acc[i][j] = floatx4{0.f, 0.f, 0.f, 0.f};

  for (int k0 = 0; k0 < K; k0 += 64) {
    __syncthreads();
#pragma unroll
    for (int i = 0; i < 4; i++) {
      int e = i * 256 + tid;
      int row = e >> 3, grp = e & 7;
      int gg = grp ^ (row & 7);
      async_copy16(A + (size_t)(m0 + row) * K + k0 + gg * 8, As + e * 8);
    }
#pragma unroll
    for (int i = 0; i < 4; i++) {
      int e = i * 256 + tid;
      int row = e >> 3, grp = e & 7;
      int gg = grp ^ (row & 7);
      async_copy16(Bt + (size_t)(n0 + row) * K + k0 + gg * 8, Bs + e * 8);
    }
    __syncthreads();
#pragma unroll
    for (int ks = 0; ks < 2; ks++) {
      bf16x8 af[4], bfr[4];
      int grp = ks * 4 + quad;
#pragma unroll
      for (int mi = 0; mi < 4; mi++) {
        int row = wm + mi * 16 + l16;
        af[mi] = *(const bf16x8*)(As + row * 64 + ((grp ^ (row & 7)) << 3));
      }
#pragma unroll
      for (int ni = 0; ni < 4; ni++) {
        int row = wn + ni * 16 + l16;
        bfr[ni] = *(const bf16x8*)(Bs + row * 64 + ((grp ^ (row & 7)) << 3));
      }
#pragma unroll
      for (int mi = 0; mi < 4; mi++)
#pragma unroll
        for (int ni = 0; ni < 4; ni++)
          acc[mi][ni] = __builtin_amdgcn_mfma_f32_16x16x32_bf16(af[mi], bfr[ni], acc[mi][ni], 0, 0, 0);
    }
  }
  // epilogue: C row = quad*4+reg (+16*mi), col = lane&15 (+16*ni)  [m89/m91 layout]
#pragma unroll
  for (int mi = 0; mi < 4; mi++) {
#pragma unroll
    for (int r = 0; r < 4; r++) {
      int row = m0 + wm + mi * 16 + quad * 4 + r;
      size_t base = (size_t)row * N + n0 + wn;
#pragma unroll
      for (int ni = 0; ni < 4; ni++)
        C[base + ni * 16 + l16] = (OUT_T)acc[mi][ni][r];
    }
  }
}

// ---------------------------------------------------------------------------
// RoPE for K only (Q-RoPE is fused into flash_attn's register load).
// qkv (4096, 3072) bf16 -> Kb (B,NKV,T,HD) roped. One thread per (row,kvh,j<64).
__global__ void rope_k(const bf16_t* __restrict__ qkv, bf16_t* __restrict__ Kb) {
  int g = blockIdx.x * 256 + threadIdx.x;
  int j = g & 63;
  int rest = g >> 6;
  int kvh = rest & 3;
  int row = rest >> 2;                // b*T + t
  int t = row & (T_ - 1);
  int b = row >> 11;                  // T_ = 2048
  const bf16_t* src = qkv + (size_t)row * NQKV + NH_ * HD_ + kvh * HD_;
  // inv_freq = 10000^(-j/64) = exp2-free fast path
  float ang = (float)t * __expf(-0.14391156816f * (float)j);
  float sn, cs;
  __sincosf(ang, &sn, &cs);
  float x0 = (float)src[j];
  float x1 = (float)src[j + 64];
  bf16_t* dst = Kb + ((size_t)(b * NKV_ + kvh) * T_ + t) * HD_;
  dst[j]      = (bf16_t)(x0 * cs - x1 * sn);
  dst[j + 64] = (bf16_t)(x1 * cs + x0 * sn);
}

// ---------------------------------------------------------------------------
// V transpose: qkv V-slice (b,t,kv,d) -> Vt (B,NKV,HD,T)
__global__ void v_transpose(const bf16_t* __restrict__ qkv, bf16_t* __restrict__ Vt) {
  __shared__ float tile[32][33];
  int t0 = blockIdx.x * 32, d0 = blockIdx.y * 32;
  int bk = blockIdx.z;
  int b = bk / NKV_, kvh = bk % NKV_;
  int tx = threadIdx.x, ty = threadIdx.y;
#pragma unroll
  for (int r = 0; r < 4; r++) {
    int t = t0 + ty + r * 8;
    tile[ty + r*8][tx] =
        (float)qkv[(size_t)(b * T_ + t) * NQKV + (NH_ + NKV_) * HD_ + kvh * HD_ + d0 + tx];
  }
  __syncthreads();
#pragma unroll
  for (int r = 0; r < 4; r++) {
    int d = d0 + ty + r * 8;
    Vt[((size_t)(b * NKV_ + kvh) * HD_ + d) * T_ + t0 + tx] = (bf16_t)tile[tx][ty + r*8];
  }
}

// ---------------------------------------------------------------------------
// Flash attention v4 + in-register Q-RoPE: S^T formulation.
// Q is read RAW from the qkv projection output; RoPE rotation is applied
// in-register at fragment-load time: the pair (d, d+64) lives in frags
// (ks, ks+2) of the SAME lane, so rotation needs no cross-lane traffic.
// 16 sincos per lane, once per block. Scale*log2e folded in here too.
// BQ=64/block, BK=64, double-buffered K/V staging, heavy-first order.
// NOTE: register sweet spot — ~90 VGPR, zero spill at 2 blocks/CU (R5/R6:
// any 2x-work-per-block variant spills or kills occupancy).
__global__ __launch_bounds__(256, 2)
void flash_attn(const bf16_t* __restrict__ qkv, const bf16_t* __restrict__ Kb,
                const bf16_t* __restrict__ Vt, bf16_t* __restrict__ Ob) {
  __shared__ __align__(16) bf16_t Ks[2][64 * 128];   // (key, d), swizzle grp^(row&15)
  __shared__ __align__(16) bf16_t Vs[2][128 * 64];   // (d, key), swizzle grp^(row&7)
  __shared__ __align__(16) bf16_t Ps[4][16 * 72];    // wave-private P^T: [q][key], +8 pad

  const int tid = threadIdx.x;
  const int wave = tid >> 6, lane = tid & 63;
  const int quad = lane >> 4, l16 = lane & 15;
  const int nQT = T_ / 64;  // 32
  const int bid = blockIdx.x;
  const int bh = bid % (B_ * NH_);
  const int qt = (nQT - 1) - (bid / (B_ * NH_));   // heavy-first
  const int h = bh % NH_;
  const int b = bh / NH_;
  const int kv = h >> 2;    // GQA: n_rep = 4

  const bf16_t* kbase = Kb + ((size_t)(b * NKV_ + kv) * T_) * HD_;
  const bf16_t* vbase = Vt + ((size_t)(b * NKV_ + kv) * HD_) * T_;

  // stage key tile kt into buffer bufi (K: 64 keys x 128 d; V^T: 128 d x 64 keys)
  auto stage = [&](int kt, int bufi) {
#pragma unroll
    for (int i = 0; i < 4; i++) {
      int e = i * 256 + tid;
      int row = e >> 4, grp = e & 15;
      int gg = grp ^ (row & 15);
      async_copy16(kbase + (size_t)(kt * 64 + row) * HD_ + gg * 8, &Ks[bufi][e * 8]);
    }
#pragma unroll
    for (int i = 0; i < 4; i++) {
      int e = i * 256 + tid;
      int row = e >> 3, grp = e & 7;
      int gg = grp ^ (row & 7);
      async_copy16(vbase + (size_t)row * T_ + kt * 64 + gg * 8, &Vs[bufi][e * 8]);
    }
  };

  stage(0, 0);  // prefetch first tile before anything else

  // Q fragments (B-operand): lane n=l16 -> q row t_row, holds d = ks*32+quad*8+j.
  // Load raw Q from qkv, apply RoPE in-register: pair (d, d+64) = frags (ks, ks+2).
  bf16x8 qf[4];
  {
    const int t_row = qt * 64 + wave * 16 + l16;
    const bf16_t* qptr = qkv + (size_t)(b * T_ + t_row) * NQKV + h * HD_;
    bf16x8 qraw[4];
#pragma unroll
    for (int ks = 0; ks < 4; ks++)
      qraw[ks] = *(const bf16x8*)(qptr + ks * 32 + quad * 8);
    const float scale = 0.12751651541057752f;  // 1/sqrt(128)*log2(e)
#pragma unroll
    for (int ks = 0; ks < 2; ks++)
#pragma unroll
      for (int j = 0; j < 8; j++) {
        int d = ks * 32 + quad * 8 + j;        // < 64
        float ang = (float)t_row * __expf(-0.14391156816f * (float)d);
        float sn, cs;
        __sincosf(ang, &sn, &cs);
        float lo = (float)qraw[ks][j], hi = (float)qraw[ks + 2][j];
        qf[ks][j]     = (bf16_t)((lo * cs - hi * sn) * scale);
        qf[ks + 2][j] = (bf16_t)((hi * cs + lo * sn) * scale);
      }
  }

  // O^T accumulators: o[dt][r] = O^T[d = dt*16+quad*4+r][q = l16]
  floatx4 o[8];
#pragma unroll
  for (int i = 0; i < 8; i++) o[i] = floatx4{0.f, 0.f, 0.f, 0.f};
  float m_s = -1e30f, l_s = 0.f;  // per-lane: this lane's q-row state

  for (int kt = 0; kt <= qt; kt++) {
    const int bufi = kt & 1;
    // barrier: (a) drains vmcnt -> staging of THIS tile (issued last iter) done;
    // (b) all waves finished compute on the buffer we are about to overwrite.
    __syncthreads();
    if (kt < qt) stage(kt + 1, bufi ^ 1);  // prefetch next tile (other buffer)

    // S^T = K Q^T : s[nt][r] = S^T[key = nt*16+quad*4+r][q = l16]
    floatx4 s[4];
#pragma unroll
    for (int nt = 0; nt < 4; nt++) s[nt] = floatx4{0.f, 0.f, 0.f, 0.f};
#pragma unroll
    for (int ks = 0; ks < 4; ks++) {
      int grp = ks * 4 + quad;
#pragma unroll
      for (int nt = 0; nt < 4; nt++) {
        int row = nt * 16 + l16;
        bf16x8 kf = *(const bf16x8*)(&Ks[bufi][row * 128 + ((grp ^ (row & 15)) << 3)]);
        s[nt] = __builtin_amdgcn_mfma_f32_16x16x32_bf16(kf, qf[ks], s[nt], 0, 0, 0);
      }
    }

    // causal mask (only the diagonal tile needs it): key_local > q_local
    if (kt == qt) {
      int qlocal = wave * 16 + l16;
#pragma unroll
      for (int nt = 0; nt < 4; nt++)
#pragma unroll
        for (int r = 0; r < 4; r++) {
          int klocal = nt * 16 + quad * 4 + r;
          if (klocal > qlocal) s[nt][r] = -1e30f;
        }
    }

    // online softmax, exp2 domain. All 16 values in this lane share one q-row;
    // full 64-key reduction = in-lane tree + 2 cross-quad shuffles.
    float mx = fmaxf(fmaxf(s[0][0], s[0][1]), fmaxf(s[0][2], s[0][3]));
#pragma unroll
    for (int nt = 1; nt < 4; nt++)
      mx = fmaxf(mx, fmaxf(fmaxf(s[nt][0], s[nt][1]), fmaxf(s[nt][2], s[nt][3])));
    mx = fmaxf(mx, __shfl_xor(mx, 16, 64));
    mx = fmaxf(mx, __shfl_xor(mx, 32, 64));
    float mnew = fmaxf(m_s, mx);
    float alpha = __builtin_amdgcn_exp2f(m_s - mnew);
    m_s = mnew;
    float sum = 0.f;
#pragma unroll
    for (int nt = 0; nt < 4; nt++)
#pragma unroll
      for (int r = 0; r < 4; r++) {
        float p = __builtin_amdgcn_exp2f(s[nt][r] - mnew);
        s[nt][r] = p;
        sum += p;
      }
    sum += __shfl_xor(sum, 16, 64);
    sum += __shfl_xor(sum, 32, 64);
    l_s = l_s * alpha + sum;
#pragma unroll
    for (int dt = 0; dt < 8; dt++) o[dt] *= alpha;

    // P^T -> LDS: row q=l16, keys nt*16+quad*4..+3 packed as one 8B write
#pragma unroll
    for (int nt = 0; nt < 4; nt++) {
      bf16x4 p4;
#pragma unroll
      for (int r = 0; r < 4; r++) p4[r] = (bf16_t)s[nt][r];
      *(bf16x4*)(&Ps[wave][l16 * 72 + nt * 16 + quad * 4]) = p4;
    }

    // O^T += V^T P^T : A = Vs (d,key) as stored; B = P^T rows (8 keys/lane)
#pragma unroll
    for (int ks = 0; ks < 2; ks++) {
      bf16x8 pf = *(const bf16x8*)(&Ps[wave][l16 * 72 + ks * 32 + quad * 8]);
      int grp = ks * 4 + quad;
#pragma unroll
      for (int dt = 0; dt < 8; dt++) {
        int row = dt * 16 + l16;
        bf16x8 vf = *(const bf16x8*)(&Vs[bufi][row * 64 + ((grp ^ (row & 7)) << 3)]);
        o[dt] = __builtin_amdgcn_mfma_f32_16x16x32_bf16(vf, pf, o[dt], 0, 0, 0);
      }
    }
  }

  // epilogue: lane owns q-row qg = qt*64 + wave*16 + l16; d = dt*16+quad*4+r.
  {
    int qg = qt * 64 + wave * 16 + l16;
    float inv_l = 1.f / l_s;
    size_t base = ((size_t)(b * T_) + qg) * D_ + h * HD_;
#pragma unroll
    for (int dt = 0; dt < 8; dt++) {
      bf16x4 w;
#pragma unroll
      for (int r = 0; r < 4; r++) w[r] = (bf16_t)(o[dt][r] * inv_l);
      *(bf16x4*)(Ob + base + dt * 16 + quad * 4) = w;
    }
  }
}

// ---------------------------------------------------------------------------
extern "C" void kernel_launch(void* const* d_in, const int* in_sizes, int n_in,
                              void* d_out, int out_size, void* d_ws, size_t ws_size,
                              hipStream_t stream) {
  const float* x  = (const float*)d_in[0];
  const float* wq = (const float*)d_in[1];
  const float* wk = (const float*)d_in[2];
  const float* wv = (const float*)d_in[3];
  const float* wo = (const float*)d_in[4];
  float* out = (float*)d_out;

  // workspace layout (bf16 elems); attn output aliases x_bf (x_bf dead after GEMM1)
  bf16_t* x_bf   = (bf16_t*)d_ws;                          // 4096*2048
  bf16_t* attn_o = x_bf;                                   // alias
  bf16_t* wqkv_t = x_bf + (size_t)MROWS * D_;              // 3072*2048
  bf16_t* wo_t   = wqkv_t + (size_t)NQKV * D_;             // 2048*2048
  bf16_t* qkv    = wo_t + (size_t)D_ * D_;                 // 4096*3072
  bf16_t* Kb     = qkv + (size_t)MROWS * NQKV;             // 2*4*2048*128
  bf16_t* Vt     = Kb + (size_t)B_ * NKV_ * T_ * HD_;      // 2*4*128*2048

  // 1. fused prep: x cast + all 4 weight transposes in ONE dispatch
  prep_fused<<<dim3(64, 64, 5), dim3(32, 8), 0, stream>>>(
      wq, wk, wv, wo, x,
      wqkv_t, wqkv_t + (size_t)2048 * D_, wqkv_t + (size_t)2560 * D_, wo_t, x_bf);

  // 2. fused QKV projection: (4096,2048) x (2048,3072) -> bf16
  gemm_bt<bf16_t><<<(MROWS / 128) * (NQKV / 128), 256, 0, stream>>>(
      x_bf, wqkv_t, qkv, MROWS, NQKV, D_);

  // 3. K-RoPE + V transpose (Q-RoPE fused into flash)
  rope_k<<<(MROWS * NKV_ * 64) / 256, 256, 0, stream>>>(qkv, Kb);
  v_transpose<<<dim3(T_ / 32, HD_ / 32, B_ * NKV_), dim3(32, 8), 0, stream>>>(qkv, Vt);

  // 4. causal flash attention: v4 + in-register Q-RoPE
  flash_attn<<<B_ * NH_ * (T_ / 64), 256, 0, stream>>>(qkv, Kb, Vt, attn_o);

  // 5. output projection: (4096,2048) x (2048,2048) -> fp32
  gemm_bt<float><<<(MROWS / 128) * (D_ / 128), 256, 0, stream>>>(
      attn_o, wo_t, out, MROWS, D_, D_);
}